// Round 10
// baseline (862.847 us; speedup 1.0000x reference)
//
#include <hip/hip_runtime.h>

typedef unsigned short u16;
typedef u16 u16x4 __attribute__((ext_vector_type(4)));
typedef u16 u16x8 __attribute__((ext_vector_type(8)));
typedef __bf16 bf16x8 __attribute__((ext_vector_type(8)));
typedef float f32x4 __attribute__((ext_vector_type(4)));

#define MFMA16 __builtin_amdgcn_mfma_f32_16x16x32_bf16
#define QSCALE 0.17677669529663689f
#define VMWAIT(N) asm volatile("s_waitcnt vmcnt(" #N ")" ::: "memory")

__device__ __forceinline__ u16 f2bf(float f) {
  unsigned u = __builtin_bit_cast(unsigned, f);
  u += 0x7fffu + ((u >> 16) & 1u);
  return (u16)(u >> 16);
}
__device__ __forceinline__ bf16x8 as_bf(u16x8 u) { return __builtin_bit_cast(bf16x8, u); }
__device__ __forceinline__ f32x4 zf4() { f32x4 z = {0.f, 0.f, 0.f, 0.f}; return z; }

template <int CTRL>
__device__ __forceinline__ float dppf(float x) {
  int i = __builtin_bit_cast(int, x);
  int r = __builtin_amdgcn_update_dpp(i, i, CTRL, 0xf, 0xf, false);
  return __builtin_bit_cast(float, r);
}
__device__ __forceinline__ float rmax16(float x) {
  x = fmaxf(x, dppf<0xB1>(x));
  x = fmaxf(x, dppf<0x4E>(x));
  x = fmaxf(x, dppf<0x124>(x));
  x = fmaxf(x, dppf<0x128>(x));
  return x;
}
__device__ __forceinline__ float rsum16(float x) {
  x += dppf<0xB1>(x);
  x += dppf<0x4E>(x);
  x += dppf<0x124>(x);
  x += dppf<0x128>(x);
  return x;
}

// ---------------- prep: weight transpose->bf16, smask2 build ---------------
__global__ __launch_bounds__(256) void prep_kernel(
    const float* __restrict__ wq, const float* __restrict__ wp,
    const float* __restrict__ bt, const int* __restrict__ ri,
    const float* __restrict__ mask,
    u16* __restrict__ wqT, u16* __restrict__ wpT, float* __restrict__ smask2) {
  int idx = blockIdx.x * 256 + threadIdx.x;
  if (idx < 442368) {
    int nn = idx / 384, kk = idx % 384;
    wqT[idx] = f2bf(wq[(size_t)kk * 1152 + nn]);
  } else if (idx < 589824) {
    int i2 = idx - 442368;
    int nn = i2 / 384, kk = i2 % 384;
    wpT[i2] = f2bf(wp[(size_t)kk * 384 + nn]);
  } else if (idx < 740352) {
    int i3 = idx - 589824;
    int g = i3 / 37632;
    int rem = i3 % 37632;
    int h = rem / 3136;
    int nm = rem % 3136;
    int n = nm >> 6;
    int r2 = nm & 63;
    int lane = r2 >> 2, nj = r2 & 3;
    int m = nj * 16 + lane;
    float v = 0.f;
    if (m < 49 && n < 49)
      v = bt[ri[n * 49 + m] * 12 + h] + mask[g * 2401 + n * 49 + m];
    smask2[i3] = v;
  }
}

// ---------------- conv_x: fp32 x -> bf16 (one pass) ------------------------
__global__ __launch_bounds__(256) void conv_x(const float* __restrict__ x,
                                              u16* __restrict__ xb) {
  size_t i = ((size_t)blockIdx.x * 256 + threadIdx.x) * 8;
  f32x4 a = *(const f32x4*)(x + i);
  f32x4 b = *(const f32x4*)(x + i + 4);
  u16x8 o;
  o[0] = f2bf(a[0]); o[1] = f2bf(a[1]); o[2] = f2bf(a[2]); o[3] = f2bf(a[3]);
  o[4] = f2bf(b[0]); o[5] = f2bf(b[1]); o[6] = f2bf(b[2]); o[7] = f2bf(b[3]);
  *(u16x8*)(xb + i) = o;
}

// ---------------- GEMM v6: gemm4 skeleton, depth-3 pipeline ---------------
// Identical to verified gemm4 except 3 LDS buffers (48 KB) and steady-state
// VMWAIT(8): each tile's loads get ~2 compute phases to land.
template <int NCH, bool QKV>
__global__ __launch_bounds__(256) void gemm6(
    const u16* __restrict__ Wt, const u16* __restrict__ Xb,
    const float* __restrict__ bias, void* __restrict__ outp) {
  __shared__ u16 As[3][128 * 32];
  __shared__ u16 Bs[3][128 * 32];
  const int t = threadIdx.x;
  const int l = t & 63, w = t >> 6;

  const int bid = blockIdx.x;
  const int xcd = bid & 7, q = bid >> 3;
  const int logical = xcd * (196 * NCH) + q;
  const int tokt = logical / NCH, cht = logical % NCH;
  const int tb = tokt * 128;
  const int cb = cht * 128;
  const int LDC = NCH * 128;

  f32x4 acc[4][4];
#pragma unroll
  for (int mi = 0; mi < 4; ++mi)
#pragma unroll
    for (int ni = 0; ni < 4; ++ni) acc[mi][ni] = zf4();

  const int rA = (w >> 1) * 64 + (l & 15);
  const int rB = (w & 1) * 64 + (l & 15);
  const int gsel = l >> 4;
  const int gA = ((gsel ^ ((rA >> 1) & 3))) * 8;
  const int gB = ((gsel ^ ((rB >> 1) & 3))) * 8;

  auto stage = [&](int bf, int kt) {
    const int ko = kt * 32;
#pragma unroll
    for (int j = 0; j < 2; ++j) {
      const int gi = j * 256 + t;
      const int row = gi >> 2, slot = gi & 3;
      const int sg = (slot ^ ((row >> 1) & 3)) * 8;
      __builtin_amdgcn_global_load_lds(
          (const __attribute__((address_space(1))) unsigned int*)
              (Wt + (size_t)(cb + row) * 384 + ko + sg),
          (__attribute__((address_space(3))) unsigned int*)(&As[bf][gi * 8]),
          16, 0, 0);
      __builtin_amdgcn_global_load_lds(
          (const __attribute__((address_space(1))) unsigned int*)
              (Xb + (size_t)(tb + row) * 384 + ko + sg),
          (__attribute__((address_space(3))) unsigned int*)(&Bs[bf][gi * 8]),
          16, 0, 0);
    }
  };

  auto kbody = [&](int cur, int ktnext, bool dostage) {
    __builtin_amdgcn_sched_barrier(0);
    __builtin_amdgcn_s_barrier();
    bf16x8 af[4], bfr[4];
#pragma unroll
    for (int mi = 0; mi < 4; ++mi)
      af[mi] = *(const bf16x8*)(&As[cur][(rA + mi * 16) * 32 + gA]);
#pragma unroll
    for (int nj = 0; nj < 4; ++nj)
      bfr[nj] = *(const bf16x8*)(&Bs[cur][(rB + nj * 16) * 32 + gB]);
    asm volatile("s_waitcnt lgkmcnt(0)" ::: "memory");
    __builtin_amdgcn_sched_barrier(0);
    __builtin_amdgcn_s_barrier();
    if (dostage) stage(cur, ktnext);
    __builtin_amdgcn_sched_barrier(0);
    __builtin_amdgcn_s_setprio(1);
#pragma unroll
    for (int mi = 0; mi < 4; ++mi)
#pragma unroll
      for (int nj = 0; nj < 4; ++nj)
        acc[mi][nj] = MFMA16(af[mi], bfr[nj], acc[mi][nj], 0, 0, 0);
    __builtin_amdgcn_s_setprio(0);
  };

  stage(0, 0);
  stage(1, 1);
  stage(2, 2);
#pragma unroll
  for (int kt = 0; kt < 9; ++kt) {
    VMWAIT(8);
    kbody(kt % 3, kt + 3, true);
  }
  VMWAIT(8);
  kbody(0, 0, false);
  VMWAIT(4);
  kbody(1, 0, false);
  VMWAIT(0);
  kbody(2, 0, false);

#pragma unroll
  for (int mi = 0; mi < 4; ++mi) {
    const int ch = cb + (w >> 1) * 64 + mi * 16 + (l >> 4) * 4;
    const f32x4 bv = *(const f32x4*)(bias + ch);
#pragma unroll
    for (int nj = 0; nj < 4; ++nj) {
      const int tok = tb + (w & 1) * 64 + nj * 16 + (l & 15);
      if constexpr (QKV) {
        const float scl = (ch < 384) ? QSCALE : 1.0f;
        u16x4 pk;
#pragma unroll
        for (int r = 0; r < 4; ++r) pk[r] = f2bf((acc[mi][nj][r] + bv[r]) * scl);
        *(u16x4*)((u16*)outp + (size_t)tok * LDC + ch) = pk;
      } else {
        f32x4 o;
#pragma unroll
        for (int r = 0; r < 4; ++r) o[r] = acc[mi][nj][r] + bv[r];
        *(f32x4*)((float*)outp + (size_t)tok * LDC + ch) = o;
      }
    }
  }
}

// ---------------- Fused attention + proj: 1 block = 1 window ---------------
// 12 waves = 12 heads (attn phase), then same 12 waves compute proj output
// channels [wv*32, wv*32+32).  O staged bf16 in the dead P region with
// granule-XOR swizzle; proj A = wpT from L2; out written directly (fp32).
__global__ __launch_bounds__(768, 3) void attn_proj_kernel(
    const u16* __restrict__ qkvb, const float* __restrict__ smask2,
    const u16* __restrict__ wpT, const float* __restrict__ bproj,
    float* __restrict__ out) {
  __shared__ u16 Pl[12][4096];     // per-head P; later reused as O staging
  __shared__ u16 Vt[12][2336];     // per-head V^T: [d][k] stride 72 + skew
  const int t = threadIdx.x;
  const int l = t & 63, wv = t >> 6;
  const int bid = blockIdx.x;
  const int b = (bid & 7) * 512 + (bid >> 3);   // window, XCD-affine
  const int h = wv;
  u16* Pw = &Pl[wv][0];
  u16* Vw = &Vt[wv][0];
  u16* Ost = &Pl[0][0];            // O staging: [tok 64][k 384], swizzled
  const u16x8 z = {0, 0, 0, 0, 0, 0, 0, 0};

  // V^T staging
#pragma unroll
  for (int i = 0; i < 4; ++i) {
    const int row = i * 16 + (l >> 2);
    const int sg = l & 3;
    u16x8 vv = z;
    if (row < 49)
      vv = *(const u16x8*)(qkvb + (size_t)(b * 49 + row) * 1152 + 768 + h * 32 + sg * 8);
#pragma unroll
    for (int e = 0; e < 8; ++e) {
      const int d = sg * 8 + e;
      Vw[d * 72 + (d >> 3) * 8 + row] = vv[e];
    }
  }

  // q / k fragments from global
  const u16* base = qkvb + (size_t)b * 49 * 1152 + h * 32 + (l >> 4) * 8;
  bf16x8 qa[4], kb[4];
#pragma unroll
  for (int mi = 0; mi < 4; ++mi) {
    const int n = mi * 16 + (l & 15);
    qa[mi] = (n < 49) ? *(const bf16x8*)(base + (size_t)n * 1152) : as_bf(z);
    kb[mi] = (n < 49) ? *(const bf16x8*)(base + 384 + (size_t)n * 1152) : as_bf(z);
  }

  // S = q k^T
  f32x4 s[4][4];
  __builtin_amdgcn_s_setprio(1);
#pragma unroll
  for (int mi = 0; mi < 4; ++mi)
#pragma unroll
    for (int nj = 0; nj < 4; ++nj) s[mi][nj] = MFMA16(qa[mi], kb[nj], zf4(), 0, 0, 0);
  __builtin_amdgcn_s_setprio(0);

  // bias + shift mask
  const float* sm2 = smask2 + ((size_t)(b & 3) * 12 + h) * 3136;
#pragma unroll
  for (int mi = 0; mi < 4; ++mi) {
#pragma unroll
    for (int r = 0; r < 4; ++r) {
      const int n = mi * 16 + (l >> 4) * 4 + r;
      if (n < 49) {
        const f32x4 bv = *(const f32x4*)(sm2 + n * 64 + (l & 15) * 4);
        s[mi][0][r] += bv[0];
        s[mi][1][r] += bv[1];
        s[mi][2][r] += bv[2];
        s[mi][3][r] = ((l & 15) == 0) ? s[mi][3][r] + bv[3] : -1e30f;
      }
    }
  }
  // softmax
#pragma unroll
  for (int mi = 0; mi < 4; ++mi) {
#pragma unroll
    for (int r = 0; r < 4; ++r) {
      float mx = fmaxf(fmaxf(s[mi][0][r], s[mi][1][r]), fmaxf(s[mi][2][r], s[mi][3][r]));
      mx = rmax16(mx);
      float e0 = 0.f;
#pragma unroll
      for (int nj = 0; nj < 4; ++nj) {
        const float p = __expf(s[mi][nj][r] - mx);
        s[mi][nj][r] = p;
        e0 += p;
      }
      e0 = rsum16(e0);
      const float inv = 1.0f / e0;
#pragma unroll
      for (int nj = 0; nj < 4; ++nj) s[mi][nj][r] *= inv;
    }
  }
  // P -> LDS (compact [64][64] swizzle, r7/r9-verified)
#pragma unroll
  for (int mi = 0; mi < 4; ++mi)
#pragma unroll
    for (int r = 0; r < 4; ++r) {
      const int row = mi * 16 + (l >> 4) * 4 + r;
#pragma unroll
      for (int nj = 0; nj < 4; ++nj) {
        const int col = nj * 16 + (l & 15);
        Pw[row * 64 + (((col >> 3) ^ (row & 7)) * 8) + (col & 7)] = f2bf(s[mi][nj][r]);
      }
    }
  asm volatile("s_waitcnt lgkmcnt(0)" ::: "memory");
  __builtin_amdgcn_sched_barrier(0);

  // O^T[d][n] = sum_k V^T[d][k] P^T[k][n]
  f32x4 ot[2][4];
#pragma unroll
  for (int dj = 0; dj < 2; ++dj)
#pragma unroll
    for (int mi = 0; mi < 4; ++mi) ot[dj][mi] = zf4();
#pragma unroll
  for (int ks = 0; ks < 2; ++ks) {
    bf16x8 va[2], pb[4];
#pragma unroll
    for (int dj = 0; dj < 2; ++dj) {
      const int d0 = dj * 16 + (l & 15);
      va[dj] = *(const bf16x8*)(Vw + d0 * 72 + (d0 >> 3) * 8 + ks * 32 + (l >> 4) * 8);
    }
#pragma unroll
    for (int mi = 0; mi < 4; ++mi) {
      const int row = mi * 16 + (l & 15);
      pb[mi] = *(const bf16x8*)(Pw + row * 64 + (((ks * 4 + (l >> 4)) ^ (l & 7)) * 8));
    }
    __builtin_amdgcn_s_setprio(1);
#pragma unroll
    for (int dj = 0; dj < 2; ++dj)
#pragma unroll
      for (int mi = 0; mi < 4; ++mi)
        ot[dj][mi] = MFMA16(va[dj], pb[mi], ot[dj][mi], 0, 0, 0);
    __builtin_amdgcn_s_setprio(0);
  }

  // all waves' P/V reads retired before O staging overwrites the P region
  __syncthreads();

  // stage O bf16: [tok][k=384], granule-XOR swizzle within 8-granule groups
#pragma unroll
  for (int dj = 0; dj < 2; ++dj)
#pragma unroll
    for (int mi = 0; mi < 4; ++mi) {
      const int n = mi * 16 + (l & 15);
      if (n < 49) {
        const int k0 = wv * 32 + dj * 16 + (l >> 4) * 4;
        const int g = k0 >> 3;
        const int swg = (g & ~7) | ((g & 7) ^ (n & 7));
        u16x4 pk;
        pk[0] = f2bf(ot[dj][mi][0]);
        pk[1] = f2bf(ot[dj][mi][1]);
        pk[2] = f2bf(ot[dj][mi][2]);
        pk[3] = f2bf(ot[dj][mi][3]);
        *(u16x4*)(Ost + n * 384 + swg * 8 + (k0 & 7)) = pk;
      }
    }
  __syncthreads();

  // proj: out channels [wv*32, wv*32+32), D = wpT-frags x O-frags over K=384
  f32x4 pacc[2][4];
#pragma unroll
  for (int mi = 0; mi < 2; ++mi)
#pragma unroll
    for (int nj = 0; nj < 4; ++nj) pacc[mi][nj] = zf4();
#pragma unroll
  for (int ks = 0; ks < 12; ++ks) {
    bf16x8 wa[2], ob[4];
#pragma unroll
    for (int mi = 0; mi < 2; ++mi)
      wa[mi] = *(const bf16x8*)(wpT + (size_t)(wv * 32 + mi * 16 + (l & 15)) * 384 + ks * 32 + (l >> 4) * 8);
#pragma unroll
    for (int nj = 0; nj < 4; ++nj) {
      const int tok = nj * 16 + (l & 15);
      const int g = ks * 4 + (l >> 4);
      const int swg = (g & ~7) | ((g & 7) ^ (tok & 7));
      ob[nj] = *(const bf16x8*)(Ost + tok * 384 + swg * 8);
    }
    __builtin_amdgcn_s_setprio(1);
#pragma unroll
    for (int mi = 0; mi < 2; ++mi)
#pragma unroll
      for (int nj = 0; nj < 4; ++nj)
        pacc[mi][nj] = MFMA16(wa[mi], ob[nj], pacc[mi][nj], 0, 0, 0);
    __builtin_amdgcn_s_setprio(0);
  }
  // store out fp32 (+bias): lane holds D[ch..ch+3][tok]
#pragma unroll
  for (int mi = 0; mi < 2; ++mi) {
    const int ch = wv * 32 + mi * 16 + (l >> 4) * 4;
    const f32x4 bv = *(const f32x4*)(bproj + ch);
#pragma unroll
    for (int nj = 0; nj < 4; ++nj) {
      const int tok = nj * 16 + (l & 15);
      if (tok < 49) {
        f32x4 o;
#pragma unroll
        for (int r = 0; r < 4; ++r) o[r] = pacc[mi][nj][r] + bv[r];
        *(f32x4*)(out + (size_t)(b * 49 + tok) * 384 + ch) = o;
      }
    }
  }
}

extern "C" void kernel_launch(void* const* d_in, const int* in_sizes, int n_in,
                              void* d_out, int out_size, void* d_ws, size_t ws_size,
                              hipStream_t stream) {
  const float* x       = (const float*)d_in[0];
  const float* mask    = (const float*)d_in[1];
  const float* w_qkv   = (const float*)d_in[2];
  const float* b_qkv   = (const float*)d_in[3];
  const float* bias_t  = (const float*)d_in[4];
  const float* w_proj  = (const float*)d_in[5];
  const float* b_proj  = (const float*)d_in[6];
  const int*   rel_idx = (const int*)d_in[7];
  float* out = (float*)d_out;

  char* ws = (char*)d_ws;
  u16*   wqT    = (u16*)ws;                      // 442368 u16
  u16*   wpT    = (u16*)(ws + 884736);           // 147456 u16
  float* smask2 = (float*)(ws + 1179648);        // 150528 f32 (602112 B)
  u16*   qkvb   = (u16*)(ws + 1781760);          // 200704*1152 u16
  u16*   xb     = (u16*)(ws + 464203776);        // 200704*384 u16

  prep_kernel<<<2892, 256, 0, stream>>>(w_qkv, w_proj, bias_t, rel_idx, mask,
                                        wqT, wpT, smask2);
  conv_x<<<37632, 256, 0, stream>>>(x, xb);
  gemm6<9, true><<<14112, 256, 0, stream>>>(wqT, xb, b_qkv, qkvb);
  attn_proj_kernel<<<4096, 768, 0, stream>>>(qkvb, smask2, wpT, b_proj, out);
}

// Round 11
// 795.698 us; speedup vs baseline: 1.0844x; 1.0844x over previous
//
#include <hip/hip_runtime.h>

typedef unsigned short u16;
typedef u16 u16x4 __attribute__((ext_vector_type(4)));
typedef u16 u16x8 __attribute__((ext_vector_type(8)));
typedef __bf16 bf16x8 __attribute__((ext_vector_type(8)));
typedef float f32x4 __attribute__((ext_vector_type(4)));

#define MFMA16 __builtin_amdgcn_mfma_f32_16x16x32_bf16
#define QSCALE 0.17677669529663689f
#define VMWAIT(N) asm volatile("s_waitcnt vmcnt(" #N ")" ::: "memory")

__device__ __forceinline__ u16 f2bf(float f) {
  unsigned u = __builtin_bit_cast(unsigned, f);
  u += 0x7fffu + ((u >> 16) & 1u);
  return (u16)(u >> 16);
}
__device__ __forceinline__ bf16x8 as_bf(u16x8 u) { return __builtin_bit_cast(bf16x8, u); }
__device__ __forceinline__ f32x4 zf4() { f32x4 z = {0.f, 0.f, 0.f, 0.f}; return z; }

template <int CTRL>
__device__ __forceinline__ float dppf(float x) {
  int i = __builtin_bit_cast(int, x);
  int r = __builtin_amdgcn_update_dpp(i, i, CTRL, 0xf, 0xf, false);
  return __builtin_bit_cast(float, r);
}
__device__ __forceinline__ float rmax16(float x) {
  x = fmaxf(x, dppf<0xB1>(x));
  x = fmaxf(x, dppf<0x4E>(x));
  x = fmaxf(x, dppf<0x124>(x));
  x = fmaxf(x, dppf<0x128>(x));
  return x;
}
__device__ __forceinline__ float rsum16(float x) {
  x += dppf<0xB1>(x);
  x += dppf<0x4E>(x);
  x += dppf<0x124>(x);
  x += dppf<0x128>(x);
  return x;
}

// ---------------- prep: weight transpose->bf16, smask2 build ---------------
__global__ __launch_bounds__(256) void prep_kernel(
    const float* __restrict__ wq, const float* __restrict__ wp,
    const float* __restrict__ bt, const int* __restrict__ ri,
    const float* __restrict__ mask,
    u16* __restrict__ wqT, u16* __restrict__ wpT, float* __restrict__ smask2) {
  int idx = blockIdx.x * 256 + threadIdx.x;
  if (idx < 442368) {
    int nn = idx / 384, kk = idx % 384;
    wqT[idx] = f2bf(wq[(size_t)kk * 1152 + nn]);
  } else if (idx < 589824) {
    int i2 = idx - 442368;
    int nn = i2 / 384, kk = i2 % 384;
    wpT[i2] = f2bf(wp[(size_t)kk * 384 + nn]);
  } else if (idx < 740352) {
    int i3 = idx - 589824;
    int g = i3 / 37632;
    int rem = i3 % 37632;
    int h = rem / 3136;
    int nm = rem % 3136;
    int n = nm >> 6;
    int r2 = nm & 63;
    int lane = r2 >> 2, nj = r2 & 3;
    int m = nj * 16 + lane;
    float v = 0.f;
    if (m < 49 && n < 49)
      v = bt[ri[n * 49 + m] * 12 + h] + mask[g * 2401 + n * 49 + m];
    smask2[i3] = v;
  }
}

// ---------------- conv_x: fp32 x -> bf16 (one pass) ------------------------
__global__ __launch_bounds__(256) void conv_x(const float* __restrict__ x,
                                              u16* __restrict__ xb) {
  size_t i = ((size_t)blockIdx.x * 256 + threadIdx.x) * 8;
  f32x4 a = *(const f32x4*)(x + i);
  f32x4 b = *(const f32x4*)(x + i + 4);
  u16x8 o;
  o[0] = f2bf(a[0]); o[1] = f2bf(a[1]); o[2] = f2bf(a[2]); o[3] = f2bf(a[3]);
  o[4] = f2bf(b[0]); o[5] = f2bf(b[1]); o[6] = f2bf(b[2]); o[7] = f2bf(b[3]);
  *(u16x8*)(xb + i) = o;
}

// ---------------- GEMM v6 (r10-verified): C^T, BK=32, depth-3 pipeline -----
template <int NCH, bool QKV>
__global__ __launch_bounds__(256) void gemm6(
    const u16* __restrict__ Wt, const u16* __restrict__ Xb,
    const float* __restrict__ bias, void* __restrict__ outp) {
  __shared__ u16 As[3][128 * 32];
  __shared__ u16 Bs[3][128 * 32];
  const int t = threadIdx.x;
  const int l = t & 63, w = t >> 6;

  const int bid = blockIdx.x;
  const int xcd = bid & 7, q = bid >> 3;
  const int logical = xcd * (196 * NCH) + q;
  const int tokt = logical / NCH, cht = logical % NCH;
  const int tb = tokt * 128;
  const int cb = cht * 128;
  const int LDC = NCH * 128;

  f32x4 acc[4][4];
#pragma unroll
  for (int mi = 0; mi < 4; ++mi)
#pragma unroll
    for (int ni = 0; ni < 4; ++ni) acc[mi][ni] = zf4();

  const int rA = (w >> 1) * 64 + (l & 15);
  const int rB = (w & 1) * 64 + (l & 15);
  const int gsel = l >> 4;
  const int gA = ((gsel ^ ((rA >> 1) & 3))) * 8;
  const int gB = ((gsel ^ ((rB >> 1) & 3))) * 8;

  auto stage = [&](int bf, int kt) {
    const int ko = kt * 32;
#pragma unroll
    for (int j = 0; j < 2; ++j) {
      const int gi = j * 256 + t;
      const int row = gi >> 2, slot = gi & 3;
      const int sg = (slot ^ ((row >> 1) & 3)) * 8;
      __builtin_amdgcn_global_load_lds(
          (const __attribute__((address_space(1))) unsigned int*)
              (Wt + (size_t)(cb + row) * 384 + ko + sg),
          (__attribute__((address_space(3))) unsigned int*)(&As[bf][gi * 8]),
          16, 0, 0);
      __builtin_amdgcn_global_load_lds(
          (const __attribute__((address_space(1))) unsigned int*)
              (Xb + (size_t)(tb + row) * 384 + ko + sg),
          (__attribute__((address_space(3))) unsigned int*)(&Bs[bf][gi * 8]),
          16, 0, 0);
    }
  };

  auto kbody = [&](int cur, int ktnext, bool dostage) {
    __builtin_amdgcn_sched_barrier(0);
    __builtin_amdgcn_s_barrier();
    bf16x8 af[4], bfr[4];
#pragma unroll
    for (int mi = 0; mi < 4; ++mi)
      af[mi] = *(const bf16x8*)(&As[cur][(rA + mi * 16) * 32 + gA]);
#pragma unroll
    for (int nj = 0; nj < 4; ++nj)
      bfr[nj] = *(const bf16x8*)(&Bs[cur][(rB + nj * 16) * 32 + gB]);
    asm volatile("s_waitcnt lgkmcnt(0)" ::: "memory");
    __builtin_amdgcn_sched_barrier(0);
    __builtin_amdgcn_s_barrier();
    if (dostage) stage(cur, ktnext);
    __builtin_amdgcn_sched_barrier(0);
    __builtin_amdgcn_s_setprio(1);
#pragma unroll
    for (int mi = 0; mi < 4; ++mi)
#pragma unroll
      for (int nj = 0; nj < 4; ++nj)
        acc[mi][nj] = MFMA16(af[mi], bfr[nj], acc[mi][nj], 0, 0, 0);
    __builtin_amdgcn_s_setprio(0);
  };

  stage(0, 0);
  stage(1, 1);
  stage(2, 2);
#pragma unroll
  for (int kt = 0; kt < 9; ++kt) {
    VMWAIT(8);
    kbody(kt % 3, kt + 3, true);
  }
  VMWAIT(8);
  kbody(0, 0, false);
  VMWAIT(4);
  kbody(1, 0, false);
  VMWAIT(0);
  kbody(2, 0, false);

#pragma unroll
  for (int mi = 0; mi < 4; ++mi) {
    const int ch = cb + (w >> 1) * 64 + mi * 16 + (l >> 4) * 4;
    const f32x4 bv = *(const f32x4*)(bias + ch);
#pragma unroll
    for (int nj = 0; nj < 4; ++nj) {
      const int tok = tb + (w & 1) * 64 + nj * 16 + (l & 15);
      if constexpr (QKV) {
        const float scl = (ch < 384) ? QSCALE : 1.0f;
        u16x4 pk;
#pragma unroll
        for (int r = 0; r < 4; ++r) pk[r] = f2bf((acc[mi][nj][r] + bv[r]) * scl);
        *(u16x4*)((u16*)outp + (size_t)tok * LDC + ch) = pk;
      } else {
        f32x4 o;
#pragma unroll
        for (int r = 0; r < 4; ++r) o[r] = acc[mi][nj][r] + bv[r];
        *(f32x4*)((float*)outp + (size_t)tok * LDC + ch) = o;
      }
    }
  }
}

// ---------------- Attention v11: 1 block = 1 window x 4 heads --------------
// 4 waves = 4 heads, grid = 4096 windows x 3 head-groups = 12288 blocks.
// LDS 50.75 KB -> 3 independent blocks/CU (12 waves): inter-block TLP hides
// load latency and VALU chains.  Per-wave code identical to r9-verified.
__global__ __launch_bounds__(256) void attn_kernel(
    const u16* __restrict__ qkvb, const float* __restrict__ smask2,
    u16* __restrict__ attnb) {
  __shared__ u16 Pl[4][4096];      // per-head P: [n][m] compact swizzled
  __shared__ u16 Vt[4][2336];      // per-head V^T: [d][k] stride 72 + skew
  const int t = threadIdx.x;
  const int l = t & 63, wv = t >> 6;
  const int bid = blockIdx.x;
  const int logical = (bid & 7) * 1536 + (bid >> 3);   // XCD-chunked
  const int b = logical / 3;                            // window
  const int hg = logical % 3;                           // head group
  const int h = hg * 4 + wv;
  u16* Pw = &Pl[wv][0];
  u16* Vw = &Vt[wv][0];
  const u16x8 z = {0, 0, 0, 0, 0, 0, 0, 0};

  // V^T staging: load V rows, scatter to [d][k]
#pragma unroll
  for (int i = 0; i < 4; ++i) {
    const int row = i * 16 + (l >> 2);
    const int sg = l & 3;
    u16x8 vv = z;
    if (row < 49)
      vv = *(const u16x8*)(qkvb + (size_t)(b * 49 + row) * 1152 + 768 + h * 32 + sg * 8);
#pragma unroll
    for (int e = 0; e < 8; ++e) {
      const int d = sg * 8 + e;
      Vw[d * 72 + (d >> 3) * 8 + row] = vv[e];
    }
  }

  // q (A-frag) / k (B-frag) from global
  const u16* base = qkvb + (size_t)b * 49 * 1152 + h * 32 + (l >> 4) * 8;
  bf16x8 qa[4], kb[4];
#pragma unroll
  for (int mi = 0; mi < 4; ++mi) {
    const int n = mi * 16 + (l & 15);
    qa[mi] = (n < 49) ? *(const bf16x8*)(base + (size_t)n * 1152) : as_bf(z);
    kb[mi] = (n < 49) ? *(const bf16x8*)(base + 384 + (size_t)n * 1152) : as_bf(z);
  }

  // S = q k^T
  f32x4 s[4][4];
  __builtin_amdgcn_s_setprio(1);
#pragma unroll
  for (int mi = 0; mi < 4; ++mi)
#pragma unroll
    for (int nj = 0; nj < 4; ++nj) s[mi][nj] = MFMA16(qa[mi], kb[nj], zf4(), 0, 0, 0);
  __builtin_amdgcn_s_setprio(0);

  // bias + shift mask (vectorized smask2)
  const float* sm2 = smask2 + ((size_t)(b & 3) * 12 + h) * 3136;
#pragma unroll
  for (int mi = 0; mi < 4; ++mi) {
#pragma unroll
    for (int r = 0; r < 4; ++r) {
      const int n = mi * 16 + (l >> 4) * 4 + r;
      if (n < 49) {
        const f32x4 bv = *(const f32x4*)(sm2 + n * 64 + (l & 15) * 4);
        s[mi][0][r] += bv[0];
        s[mi][1][r] += bv[1];
        s[mi][2][r] += bv[2];
        s[mi][3][r] = ((l & 15) == 0) ? s[mi][3][r] + bv[3] : -1e30f;
      }
    }
  }
  // softmax (DPP reduce over 16-lane groups)
#pragma unroll
  for (int mi = 0; mi < 4; ++mi) {
#pragma unroll
    for (int r = 0; r < 4; ++r) {
      float mx = fmaxf(fmaxf(s[mi][0][r], s[mi][1][r]), fmaxf(s[mi][2][r], s[mi][3][r]));
      mx = rmax16(mx);
      float e0 = 0.f;
#pragma unroll
      for (int nj = 0; nj < 4; ++nj) {
        const float p = __expf(s[mi][nj][r] - mx);
        s[mi][nj][r] = p;
        e0 += p;
      }
      e0 = rsum16(e0);
      const float inv = 1.0f / e0;
#pragma unroll
      for (int nj = 0; nj < 4; ++nj) s[mi][nj][r] *= inv;
    }
  }
  // P -> LDS bf16, compact swizzle: addr = row*64 + ((col>>3)^(row&7))*8 + (col&7)
#pragma unroll
  for (int mi = 0; mi < 4; ++mi)
#pragma unroll
    for (int r = 0; r < 4; ++r) {
      const int row = mi * 16 + (l >> 4) * 4 + r;
#pragma unroll
      for (int nj = 0; nj < 4; ++nj) {
        const int col = nj * 16 + (l & 15);
        Pw[row * 64 + (((col >> 3) ^ (row & 7)) * 8) + (col & 7)] = f2bf(s[mi][nj][r]);
      }
    }
  // drain this wave's LDS writes (V^T + P); waves own disjoint regions
  asm volatile("s_waitcnt lgkmcnt(0)" ::: "memory");
  __builtin_amdgcn_sched_barrier(0);

  // O^T[d][n] = sum_k V^T[d][k] P^T[k][n]
  f32x4 ot[2][4];
#pragma unroll
  for (int dj = 0; dj < 2; ++dj)
#pragma unroll
    for (int mi = 0; mi < 4; ++mi) ot[dj][mi] = zf4();
#pragma unroll
  for (int ks = 0; ks < 2; ++ks) {
    bf16x8 va[2], pb[4];
#pragma unroll
    for (int dj = 0; dj < 2; ++dj) {
      const int d0 = dj * 16 + (l & 15);
      va[dj] = *(const bf16x8*)(Vw + d0 * 72 + (d0 >> 3) * 8 + ks * 32 + (l >> 4) * 8);
    }
#pragma unroll
    for (int mi = 0; mi < 4; ++mi) {
      const int row = mi * 16 + (l & 15);
      pb[mi] = *(const bf16x8*)(Pw + row * 64 + (((ks * 4 + (l >> 4)) ^ (l & 7)) * 8));
    }
    __builtin_amdgcn_s_setprio(1);
#pragma unroll
    for (int dj = 0; dj < 2; ++dj)
#pragma unroll
      for (int mi = 0; mi < 4; ++mi)
        ot[dj][mi] = MFMA16(va[dj], pb[mi], ot[dj][mi], 0, 0, 0);
    __builtin_amdgcn_s_setprio(0);
  }
  // store O^T
#pragma unroll
  for (int dj = 0; dj < 2; ++dj)
#pragma unroll
    for (int mi = 0; mi < 4; ++mi) {
      const int n = mi * 16 + (l & 15);
      if (n < 49) {
        u16x4 pk;
        pk[0] = f2bf(ot[dj][mi][0]);
        pk[1] = f2bf(ot[dj][mi][1]);
        pk[2] = f2bf(ot[dj][mi][2]);
        pk[3] = f2bf(ot[dj][mi][3]);
        *(u16x4*)(attnb + (size_t)(b * 49 + n) * 384 + h * 32 + dj * 16 + (l >> 4) * 4) = pk;
      }
    }
}

extern "C" void kernel_launch(void* const* d_in, const int* in_sizes, int n_in,
                              void* d_out, int out_size, void* d_ws, size_t ws_size,
                              hipStream_t stream) {
  const float* x       = (const float*)d_in[0];
  const float* mask    = (const float*)d_in[1];
  const float* w_qkv   = (const float*)d_in[2];
  const float* b_qkv   = (const float*)d_in[3];
  const float* bias_t  = (const float*)d_in[4];
  const float* w_proj  = (const float*)d_in[5];
  const float* b_proj  = (const float*)d_in[6];
  const int*   rel_idx = (const int*)d_in[7];
  float* out = (float*)d_out;

  char* ws = (char*)d_ws;
  u16*   wqT    = (u16*)ws;                      // 442368 u16
  u16*   wpT    = (u16*)(ws + 884736);           // 147456 u16
  float* smask2 = (float*)(ws + 1179648);        // 150528 f32 (602112 B)
  u16*   qkvb   = (u16*)(ws + 1781760);          // 200704*1152 u16
  u16*   xb     = (u16*)(ws + 464203776);        // 200704*384 u16 (aliases attnb)
  u16*   attnb  = (u16*)(ws + 464203776);        // xb dead before attn writes

  prep_kernel<<<2892, 256, 0, stream>>>(w_qkv, w_proj, bias_t, rel_idx, mask,
                                        wqT, wpT, smask2);
  conv_x<<<37632, 256, 0, stream>>>(x, xb);
  gemm6<9, true><<<14112, 256, 0, stream>>>(wqT, xb, b_qkv, qkvb);
  attn_kernel<<<12288, 256, 0, stream>>>(qkvb, smask2, attnb);
  gemm6<3, false><<<4704, 256, 0, stream>>>(wpT, attnb, b_proj, out);
}

// Round 12
// 740.398 us; speedup vs baseline: 1.1654x; 1.0747x over previous
//
#include <hip/hip_runtime.h>

typedef unsigned short u16;
typedef u16 u16x4 __attribute__((ext_vector_type(4)));
typedef u16 u16x8 __attribute__((ext_vector_type(8)));
typedef __bf16 bf16x8 __attribute__((ext_vector_type(8)));
typedef float f32x4 __attribute__((ext_vector_type(4)));

#define MFMA16 __builtin_amdgcn_mfma_f32_16x16x32_bf16
#define QSCALE 0.17677669529663689f
#define VMWAIT(N) asm volatile("s_waitcnt vmcnt(" #N ")" ::: "memory")

__device__ __forceinline__ u16 f2bf(float f) {
  unsigned u = __builtin_bit_cast(unsigned, f);
  u += 0x7fffu + ((u >> 16) & 1u);
  return (u16)(u >> 16);
}
__device__ __forceinline__ bf16x8 as_bf(u16x8 u) { return __builtin_bit_cast(bf16x8, u); }
__device__ __forceinline__ f32x4 zf4() { f32x4 z = {0.f, 0.f, 0.f, 0.f}; return z; }

template <int CTRL>
__device__ __forceinline__ float dppf(float x) {
  int i = __builtin_bit_cast(int, x);
  int r = __builtin_amdgcn_update_dpp(i, i, CTRL, 0xf, 0xf, false);
  return __builtin_bit_cast(float, r);
}
__device__ __forceinline__ float rmax16(float x) {
  x = fmaxf(x, dppf<0xB1>(x));
  x = fmaxf(x, dppf<0x4E>(x));
  x = fmaxf(x, dppf<0x124>(x));
  x = fmaxf(x, dppf<0x128>(x));
  return x;
}
__device__ __forceinline__ float rsum16(float x) {
  x += dppf<0xB1>(x);
  x += dppf<0x4E>(x);
  x += dppf<0x124>(x);
  x += dppf<0x128>(x);
  return x;
}

// ---------------- prep: weight transpose->bf16, smask2 build ---------------
__global__ __launch_bounds__(256) void prep_kernel(
    const float* __restrict__ wq, const float* __restrict__ wp,
    const float* __restrict__ bt, const int* __restrict__ ri,
    const float* __restrict__ mask,
    u16* __restrict__ wqT, u16* __restrict__ wpT, float* __restrict__ smask2) {
  int idx = blockIdx.x * 256 + threadIdx.x;
  if (idx < 442368) {
    int nn = idx / 384, kk = idx % 384;
    wqT[idx] = f2bf(wq[(size_t)kk * 1152 + nn]);
  } else if (idx < 589824) {
    int i2 = idx - 442368;
    int nn = i2 / 384, kk = i2 % 384;
    wpT[i2] = f2bf(wp[(size_t)kk * 384 + nn]);
  } else if (idx < 740352) {
    int i3 = idx - 589824;
    int g = i3 / 37632;
    int rem = i3 % 37632;
    int h = rem / 3136;
    int nm = rem % 3136;
    int n = nm >> 6;
    int r2 = nm & 63;
    int lane = r2 >> 2, nj = r2 & 3;
    int m = nj * 16 + lane;
    float v = 0.f;
    if (m < 49 && n < 49)
      v = bt[ri[n * 49 + m] * 12 + h] + mask[g * 2401 + n * 49 + m];
    smask2[i3] = v;
  }
}

// ---------------- conv_x: fp32 x -> bf16 (one pass) ------------------------
__global__ __launch_bounds__(256) void conv_x(const float* __restrict__ x,
                                              u16* __restrict__ xb) {
  size_t i = ((size_t)blockIdx.x * 256 + threadIdx.x) * 8;
  f32x4 a = *(const f32x4*)(x + i);
  f32x4 b = *(const f32x4*)(x + i + 4);
  u16x8 o;
  o[0] = f2bf(a[0]); o[1] = f2bf(a[1]); o[2] = f2bf(a[2]); o[3] = f2bf(a[3]);
  o[4] = f2bf(b[0]); o[5] = f2bf(b[1]); o[6] = f2bf(b[2]); o[7] = f2bf(b[3]);
  *(u16x8*)(xb + i) = o;
}

// ---------------- GEMM v4 (twice-verified): C^T, BK=32, counted vmcnt ------
// QKV=true stores head-dense: qkvb[(qkv*12+h)*200704 + tok][32] (u16x4).
template <int NCH, bool QKV>
__global__ __launch_bounds__(256) void gemm4(
    const u16* __restrict__ Wt, const u16* __restrict__ Xb,
    const float* __restrict__ bias, void* __restrict__ outp) {
  __shared__ u16 As[2][128 * 32];
  __shared__ u16 Bs[2][128 * 32];
  const int t = threadIdx.x;
  const int l = t & 63, w = t >> 6;

  const int bid = blockIdx.x;
  const int xcd = bid & 7, q = bid >> 3;
  const int logical = xcd * (196 * NCH) + q;
  const int tokt = logical / NCH, cht = logical % NCH;
  const int tb = tokt * 128;
  const int cb = cht * 128;
  const int LDC = NCH * 128;

  f32x4 acc[4][4];
#pragma unroll
  for (int mi = 0; mi < 4; ++mi)
#pragma unroll
    for (int ni = 0; ni < 4; ++ni) acc[mi][ni] = zf4();

  const int rA = (w >> 1) * 64 + (l & 15);
  const int rB = (w & 1) * 64 + (l & 15);
  const int gsel = l >> 4;
  const int gA = ((gsel ^ ((rA >> 1) & 3))) * 8;
  const int gB = ((gsel ^ ((rB >> 1) & 3))) * 8;

  auto stage = [&](int bf, int kt) {
    const int ko = kt * 32;
#pragma unroll
    for (int j = 0; j < 2; ++j) {
      const int gi = j * 256 + t;
      const int row = gi >> 2, slot = gi & 3;
      const int sg = (slot ^ ((row >> 1) & 3)) * 8;
      __builtin_amdgcn_global_load_lds(
          (const __attribute__((address_space(1))) unsigned int*)
              (Wt + (size_t)(cb + row) * 384 + ko + sg),
          (__attribute__((address_space(3))) unsigned int*)(&As[bf][gi * 8]),
          16, 0, 0);
      __builtin_amdgcn_global_load_lds(
          (const __attribute__((address_space(1))) unsigned int*)
              (Xb + (size_t)(tb + row) * 384 + ko + sg),
          (__attribute__((address_space(3))) unsigned int*)(&Bs[bf][gi * 8]),
          16, 0, 0);
    }
  };

  auto kbody = [&](int cur, int ktnext, bool dostage) {
    __builtin_amdgcn_sched_barrier(0);
    __builtin_amdgcn_s_barrier();
    bf16x8 af[4], bfr[4];
#pragma unroll
    for (int mi = 0; mi < 4; ++mi)
      af[mi] = *(const bf16x8*)(&As[cur][(rA + mi * 16) * 32 + gA]);
#pragma unroll
    for (int nj = 0; nj < 4; ++nj)
      bfr[nj] = *(const bf16x8*)(&Bs[cur][(rB + nj * 16) * 32 + gB]);
    asm volatile("s_waitcnt lgkmcnt(0)" ::: "memory");
    __builtin_amdgcn_sched_barrier(0);
    __builtin_amdgcn_s_barrier();
    if (dostage) stage(cur, ktnext);
    __builtin_amdgcn_sched_barrier(0);
    __builtin_amdgcn_s_setprio(1);
#pragma unroll
    for (int mi = 0; mi < 4; ++mi)
#pragma unroll
      for (int nj = 0; nj < 4; ++nj)
        acc[mi][nj] = MFMA16(af[mi], bfr[nj], acc[mi][nj], 0, 0, 0);
    __builtin_amdgcn_s_setprio(0);
  };

  stage(0, 0);
  stage(1, 1);
#pragma unroll
  for (int kt = 0; kt < 10; ++kt) {
    VMWAIT(4);
    kbody(kt & 1, kt + 2, true);
  }
  VMWAIT(4);
  kbody(0, 0, false);
  VMWAIT(0);
  kbody(1, 0, false);

#pragma unroll
  for (int mi = 0; mi < 4; ++mi) {
    const int ch = cb + (w >> 1) * 64 + mi * 16 + (l >> 4) * 4;
    const f32x4 bv = *(const f32x4*)(bias + ch);
#pragma unroll
    for (int nj = 0; nj < 4; ++nj) {
      const int tok = tb + (w & 1) * 64 + nj * 16 + (l & 15);
      if constexpr (QKV) {
        const int qkvi = ch / 384;
        const int rem = ch - qkvi * 384;
        const int hh = rem >> 5;
        const int d = rem & 31;
        const float scl = (qkvi == 0) ? QSCALE : 1.0f;
        u16x4 pk;
#pragma unroll
        for (int r = 0; r < 4; ++r) pk[r] = f2bf((acc[mi][nj][r] + bv[r]) * scl);
        *(u16x4*)((u16*)outp + ((size_t)(qkvi * 12 + hh) * 200704 + tok) * 32 + d) = pk;
      } else {
        f32x4 o;
#pragma unroll
        for (int r = 0; r < 4; ++r) o[r] = acc[mi][nj][r] + bv[r];
        *(f32x4*)((float*)outp + (size_t)tok * LDC + ch) = o;
      }
    }
  }
}

// ---------------- Attention v12: r11 structure + head-dense qkvb -----------
// 4 waves = 4 heads, 12288 blocks, 3 blocks/CU.  All q/k/v reads now fully
// coalesced (qkvb[(qkv*12+h)*200704 + tok][32]).
__global__ __launch_bounds__(256) void attn_kernel(
    const u16* __restrict__ qkvb, const float* __restrict__ smask2,
    u16* __restrict__ attnb) {
  __shared__ u16 Pl[4][4096];      // per-head P: [n][m] compact swizzled
  __shared__ u16 Vt[4][2336];      // per-head V^T: [d][k] stride 72 + skew
  const int t = threadIdx.x;
  const int l = t & 63, wv = t >> 6;
  const int bid = blockIdx.x;
  const int logical = (bid & 7) * 1536 + (bid >> 3);   // XCD-chunked
  const int b = logical / 3;                            // window
  const int hg = logical % 3;                           // head group
  const int h = hg * 4 + wv;
  u16* Pw = &Pl[wv][0];
  u16* Vw = &Vt[wv][0];
  const u16x8 z = {0, 0, 0, 0, 0, 0, 0, 0};

  // V^T staging: coalesced row loads, scatter to [d][k]
#pragma unroll
  for (int i = 0; i < 4; ++i) {
    const int row = i * 16 + (l >> 2);
    const int sg = l & 3;
    u16x8 vv = z;
    if (row < 49)
      vv = *(const u16x8*)(qkvb + ((size_t)(24 + h) * 200704 + b * 49 + row) * 32 + sg * 8);
#pragma unroll
    for (int e = 0; e < 8; ++e) {
      const int d = sg * 8 + e;
      Vw[d * 72 + (d >> 3) * 8 + row] = vv[e];
    }
  }

  // q (A-frag) / k (B-frag): coalesced 1KB/instr reads
  const u16* qb = qkvb + ((size_t)h * 200704 + b * 49) * 32 + (l >> 4) * 8;
  const u16* kp = qkvb + ((size_t)(12 + h) * 200704 + b * 49) * 32 + (l >> 4) * 8;
  bf16x8 qa[4], kb[4];
#pragma unroll
  for (int mi = 0; mi < 4; ++mi) {
    const int n = mi * 16 + (l & 15);
    qa[mi] = (n < 49) ? *(const bf16x8*)(qb + n * 32) : as_bf(z);
    kb[mi] = (n < 49) ? *(const bf16x8*)(kp + n * 32) : as_bf(z);
  }

  // S = q k^T
  f32x4 s[4][4];
  __builtin_amdgcn_s_setprio(1);
#pragma unroll
  for (int mi = 0; mi < 4; ++mi)
#pragma unroll
    for (int nj = 0; nj < 4; ++nj) s[mi][nj] = MFMA16(qa[mi], kb[nj], zf4(), 0, 0, 0);
  __builtin_amdgcn_s_setprio(0);

  // bias + shift mask (vectorized smask2)
  const float* sm2 = smask2 + ((size_t)(b & 3) * 12 + h) * 3136;
#pragma unroll
  for (int mi = 0; mi < 4; ++mi) {
#pragma unroll
    for (int r = 0; r < 4; ++r) {
      const int n = mi * 16 + (l >> 4) * 4 + r;
      if (n < 49) {
        const f32x4 bv = *(const f32x4*)(sm2 + n * 64 + (l & 15) * 4);
        s[mi][0][r] += bv[0];
        s[mi][1][r] += bv[1];
        s[mi][2][r] += bv[2];
        s[mi][3][r] = ((l & 15) == 0) ? s[mi][3][r] + bv[3] : -1e30f;
      }
    }
  }
  // softmax (DPP reduce over 16-lane groups)
#pragma unroll
  for (int mi = 0; mi < 4; ++mi) {
#pragma unroll
    for (int r = 0; r < 4; ++r) {
      float mx = fmaxf(fmaxf(s[mi][0][r], s[mi][1][r]), fmaxf(s[mi][2][r], s[mi][3][r]));
      mx = rmax16(mx);
      float e0 = 0.f;
#pragma unroll
      for (int nj = 0; nj < 4; ++nj) {
        const float p = __expf(s[mi][nj][r] - mx);
        s[mi][nj][r] = p;
        e0 += p;
      }
      e0 = rsum16(e0);
      const float inv = 1.0f / e0;
#pragma unroll
      for (int nj = 0; nj < 4; ++nj) s[mi][nj][r] *= inv;
    }
  }
  // P -> LDS bf16, compact swizzle
#pragma unroll
  for (int mi = 0; mi < 4; ++mi)
#pragma unroll
    for (int r = 0; r < 4; ++r) {
      const int row = mi * 16 + (l >> 4) * 4 + r;
#pragma unroll
      for (int nj = 0; nj < 4; ++nj) {
        const int col = nj * 16 + (l & 15);
        Pw[row * 64 + (((col >> 3) ^ (row & 7)) * 8) + (col & 7)] = f2bf(s[mi][nj][r]);
      }
    }
  asm volatile("s_waitcnt lgkmcnt(0)" ::: "memory");
  __builtin_amdgcn_sched_barrier(0);

  // O^T[d][n] = sum_k V^T[d][k] P^T[k][n]
  f32x4 ot[2][4];
#pragma unroll
  for (int dj = 0; dj < 2; ++dj)
#pragma unroll
    for (int mi = 0; mi < 4; ++mi) ot[dj][mi] = zf4();
#pragma unroll
  for (int ks = 0; ks < 2; ++ks) {
    bf16x8 va[2], pb[4];
#pragma unroll
    for (int dj = 0; dj < 2; ++dj) {
      const int d0 = dj * 16 + (l & 15);
      va[dj] = *(const bf16x8*)(Vw + d0 * 72 + (d0 >> 3) * 8 + ks * 32 + (l >> 4) * 8);
    }
#pragma unroll
    for (int mi = 0; mi < 4; ++mi) {
      const int row = mi * 16 + (l & 15);
      pb[mi] = *(const bf16x8*)(Pw + row * 64 + (((ks * 4 + (l >> 4)) ^ (l & 7)) * 8));
    }
    __builtin_amdgcn_s_setprio(1);
#pragma unroll
    for (int dj = 0; dj < 2; ++dj)
#pragma unroll
      for (int mi = 0; mi < 4; ++mi)
        ot[dj][mi] = MFMA16(va[dj], pb[mi], ot[dj][mi], 0, 0, 0);
    __builtin_amdgcn_s_setprio(0);
  }
  // store O^T (attnb stays [tok][384] for proj)
#pragma unroll
  for (int dj = 0; dj < 2; ++dj)
#pragma unroll
    for (int mi = 0; mi < 4; ++mi) {
      const int n = mi * 16 + (l & 15);
      if (n < 49) {
        u16x4 pk;
        pk[0] = f2bf(ot[dj][mi][0]);
        pk[1] = f2bf(ot[dj][mi][1]);
        pk[2] = f2bf(ot[dj][mi][2]);
        pk[3] = f2bf(ot[dj][mi][3]);
        *(u16x4*)(attnb + (size_t)(b * 49 + n) * 384 + h * 32 + dj * 16 + (l >> 4) * 4) = pk;
      }
    }
}

extern "C" void kernel_launch(void* const* d_in, const int* in_sizes, int n_in,
                              void* d_out, int out_size, void* d_ws, size_t ws_size,
                              hipStream_t stream) {
  const float* x       = (const float*)d_in[0];
  const float* mask    = (const float*)d_in[1];
  const float* w_qkv   = (const float*)d_in[2];
  const float* b_qkv   = (const float*)d_in[3];
  const float* bias_t  = (const float*)d_in[4];
  const float* w_proj  = (const float*)d_in[5];
  const float* b_proj  = (const float*)d_in[6];
  const int*   rel_idx = (const int*)d_in[7];
  float* out = (float*)d_out;

  char* ws = (char*)d_ws;
  u16*   wqT    = (u16*)ws;                      // 442368 u16
  u16*   wpT    = (u16*)(ws + 884736);           // 147456 u16
  float* smask2 = (float*)(ws + 1179648);        // 150528 f32 (602112 B)
  u16*   qkvb   = (u16*)(ws + 1781760);          // 36*200704*32 u16 (dense)
  u16*   xb     = (u16*)(ws + 464203776);        // 200704*384 u16 (aliases attnb)
  u16*   attnb  = (u16*)(ws + 464203776);        // xb dead before attn writes

  prep_kernel<<<2892, 256, 0, stream>>>(w_qkv, w_proj, bias_t, rel_idx, mask,
                                        wqT, wpT, smask2);
  conv_x<<<37632, 256, 0, stream>>>(x, xb);
  gemm4<9, true><<<14112, 256, 0, stream>>>(wqT, xb, b_qkv, qkvb);
  attn_kernel<<<12288, 256, 0, stream>>>(qkvb, smask2, attnb);
  gemm4<3, false><<<4704, 256, 0, stream>>>(wpT, attnb, b_proj, out);
}